// Round 5
// baseline (544.747 us; speedup 1.0000x reference)
//
#include <hip/hip_runtime.h>
#include <hip/hip_bf16.h>
#include <stdint.h>

#define D 128
#define NET 2
#define CAP 32   // max stored in-edges per node per etype (deg ~ Poisson(8); true cnt still used for 1/deg)

typedef __bf16 bf16x8 __attribute__((ext_vector_type(8)));
typedef float f32x4 __attribute__((ext_vector_type(4)));
typedef short s16x8 __attribute__((ext_vector_type(8)));
typedef unsigned short us16x8 __attribute__((ext_vector_type(8)));

__device__ __forceinline__ float b2f(unsigned short u) {
  return __builtin_bit_cast(float, ((uint32_t)u) << 16);
}
__device__ __forceinline__ unsigned short f2b(float f) {
  __hip_bfloat16 h = __float2bfloat16(f);
  return __builtin_bit_cast(unsigned short, h);
}

// ---- combine weights: WTc[combo][out][in] = bf16( (W0 @ W1)^T ), bc = b0@W1 + b1 ----
// combo = et*3 + which, which in {K,Q,V}. All math fp32.
// grid: (8 i-tiles, 6 combos), 256 threads. Thread: i = it*16 + (t>>4), j-base = (t&15)*8.
__global__ void k_combine(const float* __restrict__ Wt, const float* __restrict__ bt,
                          const float* __restrict__ Kw, const float* __restrict__ Kb,
                          const float* __restrict__ Qw, const float* __restrict__ Qb,
                          const float* __restrict__ Vw, const float* __restrict__ Vb,
                          unsigned short* __restrict__ WTc, float* __restrict__ bc) {
  int combo = blockIdx.y;
  int et = combo / 3, which = combo % 3;
  const float* W0 = Wt + (size_t)et * D * D;
  const float* W1 = ((which == 0) ? Kw : (which == 1) ? Qw : Vw) + (size_t)et * D * D;
  const float* b1 = ((which == 0) ? Kb : (which == 1) ? Qb : Vb) + (size_t)et * D;
  const float* b0 = bt + (size_t)et * D;

  int t = threadIdx.x;
  int i = blockIdx.x * 16 + (t >> 4);
  int jb = (t & 15) * 8;
  float acc[8];
#pragma unroll
  for (int j = 0; j < 8; j++) acc[j] = 0.f;
  for (int k = 0; k < D; k++) {
    float a0 = W0[(size_t)i * D + k];
    const float* w1p = W1 + (size_t)k * D + jb;
#pragma unroll
    for (int j = 0; j < 8; j++) acc[j] += a0 * w1p[j];
  }
  unsigned short* wout = WTc + (size_t)combo * D * D;
#pragma unroll
  for (int j = 0; j < 8; j++) wout[(size_t)(jb + j) * D + i] = f2b(acc[j]);

  if (blockIdx.x == 0 && t < D) {
    float s = b1[t];
    for (int k = 0; k < D; k++) s += b0[k] * W1[(size_t)k * D + t];
    bc[(size_t)combo * D + t] = s;
  }
}

// ---- fused per-etype: K/Q/V = feat @ Wc + bc ; cross-head attn -> Wh (bf16) ----
// One barrier; B-fragments straight from L2 (weights 192 KB total, L2-resident).
__global__ __launch_bounds__(256, 2) void k_fused(
    const float* __restrict__ feat, const unsigned short* __restrict__ WTc,
    const float* __restrict__ bc, unsigned short* __restrict__ Whall, int nrows) {
  __shared__ unsigned short As[64][136];   // pitch 136: 16B-aligned rows
  int et = blockIdx.y;
  int tid = threadIdx.x;
  int row0 = blockIdx.x * 64;
  int w = tid >> 6, lane = tid & 63;
  int m = lane & 15, q = lane >> 4;

  {  // stage feat tile (64 x 128), fp32 -> bf16, coalesced
    int r = tid >> 2, qq = tid & 3;
    int gr = row0 + r;
    unsigned short tmp[32];
    if (gr < nrows) {
      const f32x4* gp = (const f32x4*)(feat + (size_t)gr * D + qq * 32);
#pragma unroll
      for (int i = 0; i < 8; i++) {
        f32x4 v = gp[i];
#pragma unroll
        for (int j = 0; j < 4; j++) tmp[i * 4 + j] = f2b(v[j]);
      }
    } else {
#pragma unroll
      for (int i = 0; i < 32; i++) tmp[i] = 0;
    }
    us16x8* lp = (us16x8*)&As[r][qq * 32];
#pragma unroll
    for (int i = 0; i < 4; i++) lp[i] = *(const us16x8*)&tmp[i * 8];
  }
  __syncthreads();  // the only barrier

  bf16x8 af[4];
#pragma unroll
  for (int ks = 0; ks < 4; ks++)
    af[ks] = __builtin_bit_cast(bf16x8, *(const s16x8*)&As[w * 16 + m][ks * 32 + q * 8]);

  const unsigned short* WK = WTc + (size_t)(et * 3 + 0) * D * D;
  const unsigned short* WQ = WTc + (size_t)(et * 3 + 1) * D * D;
  const unsigned short* WV = WTc + (size_t)(et * 3 + 2) * D * D;
  const float* bK = bc + (size_t)(et * 3 + 0) * D;
  const float* bQ = bc + (size_t)(et * 3 + 1) * D;
  const float* bV = bc + (size_t)(et * 3 + 2) * D;

  f32x4 kacc[8], qacc[8], vacc[8];
#pragma unroll
  for (int nt = 0; nt < 8; nt++) {
    size_t wo = (size_t)(nt * 16 + m) * D + q * 8;
    f32x4 ka = {0.f, 0.f, 0.f, 0.f}, qa = ka, va = ka;
#pragma unroll
    for (int ks = 0; ks < 4; ks++) {
      s16x8 bk = *(const s16x8*)(WK + wo + ks * 32);
      s16x8 bq = *(const s16x8*)(WQ + wo + ks * 32);
      s16x8 bv = *(const s16x8*)(WV + wo + ks * 32);
      ka = __builtin_amdgcn_mfma_f32_16x16x32_bf16(af[ks], __builtin_bit_cast(bf16x8, bk), ka, 0, 0, 0);
      qa = __builtin_amdgcn_mfma_f32_16x16x32_bf16(af[ks], __builtin_bit_cast(bf16x8, bq), qa, 0, 0, 0);
      va = __builtin_amdgcn_mfma_f32_16x16x32_bf16(af[ks], __builtin_bit_cast(bf16x8, bv), va, 0, 0, 0);
    }
    kacc[nt] = ka + bK[nt * 16 + m];
    qacc[nt] = qa + bQ[nt * 16 + m];
    vacc[nt] = va + bV[nt * 16 + m];
  }

  // ---- cross-head attention, per output row r (C layout: row=q*4+r, col=nt*16+m)
  unsigned short* Wh = Whall + (size_t)et * nrows * D;
  const float scale = 0.17677669529663687f;  // 1/sqrt(32)
#pragma unroll
  for (int r = 0; r < 4; r++) {
    float sc[4][4];
#pragma unroll
    for (int hh = 0; hh < 4; hh++)
#pragma unroll
      for (int gg = 0; gg < 4; gg++)
        sc[hh][gg] = qacc[2 * hh][r] * kacc[2 * gg][r] + qacc[2 * hh + 1][r] * kacc[2 * gg + 1][r];
    // reduce over the 16 m-lanes (lane bits 0..3; q bits untouched)
#pragma unroll
    for (int off = 1; off < 16; off <<= 1)
#pragma unroll
      for (int hh = 0; hh < 4; hh++)
#pragma unroll
        for (int gg = 0; gg < 4; gg++)
          sc[hh][gg] += __shfl_xor(sc[hh][gg], off, 64);
    float a[4][4];
#pragma unroll
    for (int hh = 0; hh < 4; hh++) {
      float s0 = sc[hh][0] * scale, s1 = sc[hh][1] * scale;
      float s2 = sc[hh][2] * scale, s3 = sc[hh][3] * scale;
      float mx = fmaxf(fmaxf(s0, s1), fmaxf(s2, s3));
      float e0 = __expf(s0 - mx), e1 = __expf(s1 - mx);
      float e2 = __expf(s2 - mx), e3 = __expf(s3 - mx);
      float inv = 1.f / (e0 + e1 + e2 + e3);
      a[hh][0] = e0 * inv; a[hh][1] = e1 * inv; a[hh][2] = e2 * inv; a[hh][3] = e3 * inv;
    }
    int grow = row0 + w * 16 + q * 4 + r;
    if (grow < nrows) {
      unsigned short* op = Wh + (size_t)grow * D;
#pragma unroll
      for (int nt = 0; nt < 8; nt++) {
        int hh = nt >> 1, lo = nt & 1;
        float o = a[hh][0] * vacc[0 + lo][r] + a[hh][1] * vacc[2 + lo][r] +
                  a[hh][2] * vacc[4 + lo][r] + a[hh][3] * vacc[6 + lo][r];
        op[nt * 16 + m] = f2b(o);
      }
    }
  }
}

// ---- bucket build: per (etype,dst) list of src ids (+et*N so Whall is one base) ----
__global__ void k_build(const int* __restrict__ src, const int* __restrict__ dst,
                        int* __restrict__ cnt, int* __restrict__ bucket, int Eper, int n) {
  int i = blockIdx.x * 256 + threadIdx.x;
  if (i >= NET * Eper) return;
  int et = i / Eper;
  int d = dst[i];
  int s = src[i];
  int key = et * n + d;
  int slot = atomicAdd(&cnt[key], 1);
  if (slot < CAP) bucket[(size_t)key * CAP + slot] = s + et * n;
}

// ---- gather + mean + residual + LayerNorm, one wave per node ----
__global__ __launch_bounds__(256) void k_gather_ln(
    const unsigned short* __restrict__ Whall, const int* __restrict__ bucket,
    const int* __restrict__ cnt, const float* __restrict__ feat,
    const float* __restrict__ g, const float* __restrict__ b,
    float* __restrict__ out, int n) {
  int lane = threadIdx.x & 63, wv = threadIdx.x >> 6;
  int node = blockIdx.x * 4 + wv;
  if (node >= n) return;

  int c0 = cnt[node], c1 = cnt[n + node];
  int c0c = min(c0, CAP), c1c = min(c1, CAP);
  float w0 = 1.0f / fmaxf((float)c0, 1.0f);
  float w1 = 1.0f / fmaxf((float)c1, 1.0f);

  // preload edge ids: lanes 0..31 hold etype-0 ids, lanes 32..63 hold etype-1 ids
  int myid = 0;
  if (lane < 32) {
    if (lane < c0c) myid = bucket[(size_t)node * CAP + lane];
  } else {
    if (lane - 32 < c1c) myid = bucket[((size_t)n + node) * CAP + (lane - 32)];
  }

  float a0 = 0.f, a1 = 0.f;  // columns 2*lane, 2*lane+1
  for (int j = 0; j < c0c; j++) {
    int sid = __shfl(myid, j, 64);
    ushort2 v = *(const ushort2*)(Whall + (size_t)sid * D + 2 * lane);
    a0 += w0 * b2f(v.x);
    a1 += w0 * b2f(v.y);
  }
  for (int j = 0; j < c1c; j++) {
    int sid = __shfl(myid, 32 + j, 64);
    ushort2 v = *(const ushort2*)(Whall + (size_t)sid * D + 2 * lane);
    a0 += w1 * b2f(v.x);
    a1 += w1 * b2f(v.y);
  }

  const float2* fp = (const float2*)(feat + (size_t)node * D);
  float2 fv = fp[lane];
  float x0 = a0 + fv.x;
  float x1 = a1 + fv.y;

  float s = x0 + x1, s2 = x0 * x0 + x1 * x1;
#pragma unroll
  for (int off = 32; off > 0; off >>= 1) {
    s += __shfl_xor(s, off, 64);
    s2 += __shfl_xor(s2, off, 64);
  }
  float mu = s * (1.0f / 128.0f);
  float var = fmaxf(s2 * (1.0f / 128.0f) - mu * mu, 0.0f);
  float rs = rsqrtf(var + 1e-5f);

  float2 gv = ((const float2*)g)[lane];
  float2 bv = ((const float2*)b)[lane];
  float2 ov;
  ov.x = (x0 - mu) * rs * gv.x + bv.x;
  ov.y = (x1 - mu) * rs * gv.y + bv.y;
  ((float2*)(out + (size_t)node * D))[lane] = ov;
}

extern "C" void kernel_launch(void* const* d_in, const int* in_sizes, int n_in,
                              void* d_out, int out_size, void* d_ws, size_t ws_size,
                              hipStream_t stream) {
  const float* feat = (const float*)d_in[0];
  const int* src = (const int*)d_in[1];
  const int* dst = (const int*)d_in[2];
  const float* Wt = (const float*)d_in[3];
  const float* bt = (const float*)d_in[4];
  const float* Kw = (const float*)d_in[5];
  const float* Kb = (const float*)d_in[6];
  const float* Qw = (const float*)d_in[7];
  const float* Qb = (const float*)d_in[8];
  const float* Vw = (const float*)d_in[9];
  const float* Vb = (const float*)d_in[10];
  const float* lng = (const float*)d_in[11];
  const float* lnb = (const float*)d_in[12];

  const int N = in_sizes[0] / D;       // 100000
  const int E = in_sizes[1] / NET;     // 800000

  // workspace: Whall 51.2MB + bucket 25.6MB + cnt 0.8MB + WTc 0.2MB + bc 3KB ~= 77.8MB
  char* p = (char*)d_ws;
  unsigned short* Whall = (unsigned short*)p;  p += (size_t)NET * N * D * 2;
  int* bucket = (int*)p;                       p += (size_t)NET * N * CAP * sizeof(int);
  int* cnt = (int*)p;                          p += (size_t)NET * N * sizeof(int);
  unsigned short* WTc = (unsigned short*)p;    p += (size_t)NET * 3 * D * D * 2;
  float* bc = (float*)p;

  hipMemsetAsync(cnt, 0, (size_t)NET * N * sizeof(int), stream);
  k_combine<<<dim3(8, NET * 3), 256, 0, stream>>>(Wt, bt, Kw, Kb, Qw, Qb, Vw, Vb, WTc, bc);
  k_build<<<(NET * E + 255) / 256, 256, 0, stream>>>(src, dst, cnt, bucket, E, N);

  int gblocks = (N + 63) / 64;
  k_fused<<<dim3(gblocks, NET), 256, 0, stream>>>(feat, WTc, bc, Whall, N);

  k_gather_ln<<<(N + 3) / 4, 256, 0, stream>>>(Whall, bucket, cnt, feat, lng, lnb,
                                               (float*)d_out, N);
}

// Round 7
// 462.110 us; speedup vs baseline: 1.1788x; 1.1788x over previous
//
#include <hip/hip_runtime.h>
#include <hip/hip_bf16.h>
#include <stdint.h>

#define D 128
#define NET 2
#define CAP 32   // max stored in-edges per node per etype (deg ~ Poisson(8); true cnt still used for 1/deg)

typedef __bf16 bf16x8 __attribute__((ext_vector_type(8)));
typedef float f32x4 __attribute__((ext_vector_type(4)));
typedef short s16x8 __attribute__((ext_vector_type(8)));
typedef unsigned short us16x8 __attribute__((ext_vector_type(8)));

__device__ __forceinline__ float b2f(unsigned short u) {
  return __builtin_bit_cast(float, ((uint32_t)u) << 16);
}
__device__ __forceinline__ unsigned short f2b(float f) {
  __hip_bfloat16 h = __float2bfloat16(f);
  return __builtin_bit_cast(unsigned short, h);
}

// ---- combine weights: WTc[combo][n][k] = bf16( (W0 @ W1)^T ), bc = b0@W1 + b1 ----
// combo = et*3 + which, which in {K,Q,V}. All math fp32.  (round-5 verbatim, passed)
__global__ void k_combine(const float* __restrict__ Wt, const float* __restrict__ bt,
                          const float* __restrict__ Kw, const float* __restrict__ Kb,
                          const float* __restrict__ Qw, const float* __restrict__ Qb,
                          const float* __restrict__ Vw, const float* __restrict__ Vb,
                          unsigned short* __restrict__ WTc, float* __restrict__ bc) {
  int combo = blockIdx.y;
  int et = combo / 3, which = combo % 3;
  const float* W0 = Wt + (size_t)et * D * D;
  const float* W1 = ((which == 0) ? Kw : (which == 1) ? Qw : Vw) + (size_t)et * D * D;
  const float* b1 = ((which == 0) ? Kb : (which == 1) ? Qb : Vb) + (size_t)et * D;
  const float* b0 = bt + (size_t)et * D;

  int t = threadIdx.x;
  int i = blockIdx.x * 16 + (t >> 4);
  int jb = (t & 15) * 8;
  float acc[8];
#pragma unroll
  for (int j = 0; j < 8; j++) acc[j] = 0.f;
  for (int k = 0; k < D; k++) {
    float a0 = W0[(size_t)i * D + k];
    const float* w1p = W1 + (size_t)k * D + jb;
#pragma unroll
    for (int j = 0; j < 8; j++) acc[j] += a0 * w1p[j];
  }
  unsigned short* wout = WTc + (size_t)combo * D * D;
#pragma unroll
  for (int j = 0; j < 8; j++) wout[(size_t)(jb + j) * D + i] = f2b(acc[j]);

  if (blockIdx.x == 0 && t < D) {
    float s = b1[t];
    for (int k = 0; k < D; k++) s += b0[k] * W1[(size_t)k * D + t];
    bc[(size_t)combo * D + t] = s;
  }
}

// stage one 128x128 bf16 weight (row-major [out][in]) into LDS, 256 threads (round-4 verbatim)
__device__ __forceinline__ void stage_w(const unsigned short* __restrict__ W,
                                        unsigned short (*Ws)[136], int tid) {
  int r = tid >> 1, hh = tid & 1;
  const us16x8* gp = (const us16x8*)(W + (size_t)r * D + hh * 64);
  us16x8* lp = (us16x8*)&Ws[r][hh * 64];
#pragma unroll
  for (int i = 0; i < 8; i++) lp[i] = gp[i];
}

// GEMM of the A-frags (af) against staged B (Ws) -> 8 x f32x4 per lane (round-4 verbatim)
__device__ __forceinline__ void gemm_frag(const bf16x8* af, unsigned short (*Ws)[136],
                                          int m, int q, f32x4* acc) {
#pragma unroll
  for (int nt = 0; nt < 8; nt++) {
    f32x4 a = {0.f, 0.f, 0.f, 0.f};
#pragma unroll
    for (int ks = 0; ks < 4; ks++) {
      s16x8 br = *(const s16x8*)&Ws[nt * 16 + m][ks * 32 + q * 8];
      a = __builtin_amdgcn_mfma_f32_16x16x32_bf16(af[ks], __builtin_bit_cast(bf16x8, br), a, 0, 0, 0);
    }
    acc[nt] = a;
  }
}

// ---- fused per-etype: K/Q/V = feat @ Wc + bc ; cross-head attn -> Wh (bf16) ----
// Round-4 staging + round-5 combined weights + register prefetch. 5 barriers.
__global__ __launch_bounds__(256) void k_fused(
    const float* __restrict__ feat, const unsigned short* __restrict__ WTc,
    const float* __restrict__ bc, unsigned short* __restrict__ Whall, int nrows) {
  __shared__ unsigned short As[64][136];
  __shared__ unsigned short Ws[128][136];
  int et = blockIdx.y;
  int tid = threadIdx.x;
  int row0 = blockIdx.x * 64;
  int w = tid >> 6, lane = tid & 63;
  int m = lane & 15, q = lane >> 4;

  const unsigned short* WK = WTc + (size_t)(et * 3 + 0) * D * D;
  const unsigned short* WQ = WTc + (size_t)(et * 3 + 1) * D * D;
  const unsigned short* WV = WTc + (size_t)(et * 3 + 2) * D * D;
  const float* bK = bc + (size_t)(et * 3 + 0) * D;
  const float* bQ = bc + (size_t)(et * 3 + 1) * D;
  const float* bV = bc + (size_t)(et * 3 + 2) * D;

  {  // stage feat tile (64 x 128), fp32 -> bf16, coalesced (round-4 verbatim)
    int r = tid >> 2, qq = tid & 3;
    int gr = row0 + r;
    unsigned short tmp[32];
    if (gr < nrows) {
      const f32x4* gp = (const f32x4*)(feat + (size_t)gr * D + qq * 32);
#pragma unroll
      for (int i = 0; i < 8; i++) {
        f32x4 v = gp[i];
#pragma unroll
        for (int j = 0; j < 4; j++) tmp[i * 4 + j] = f2b(v[j]);
      }
    } else {
#pragma unroll
      for (int i = 0; i < 32; i++) tmp[i] = 0;
    }
    us16x8* lp = (us16x8*)&As[r][qq * 32];
#pragma unroll
    for (int i = 0; i < 4; i++) lp[i] = *(const us16x8*)&tmp[i * 8];
  }
  stage_w(WK, Ws, tid);
  __syncthreads();  // B1

  bf16x8 af[4];
#pragma unroll
  for (int ks = 0; ks < 4; ks++)
    af[ks] = __builtin_bit_cast(bf16x8, *(const s16x8*)&As[w * 16 + m][ks * 32 + q * 8]);

  // prefetch WQ into registers (same addressing as stage_w) while K-GEMM runs
  int sr = tid >> 1, sh = tid & 1;
  us16x8 pf[8];
  {
    const us16x8* gp = (const us16x8*)(WQ + (size_t)sr * D + sh * 64);
#pragma unroll
    for (int i = 0; i < 8; i++) pf[i] = gp[i];
  }
  f32x4 kacc[8];
  gemm_frag(af, Ws, m, q, kacc);
#pragma unroll
  for (int nt = 0; nt < 8; nt++) kacc[nt] += bK[nt * 16 + m];
  __syncthreads();  // B2: all K reads of Ws done
  {
    us16x8* lp = (us16x8*)&Ws[sr][sh * 64];
#pragma unroll
    for (int i = 0; i < 8; i++) lp[i] = pf[i];
  }
  {  // prefetch WV during Q-GEMM
    const us16x8* gp = (const us16x8*)(WV + (size_t)sr * D + sh * 64);
#pragma unroll
    for (int i = 0; i < 8; i++) pf[i] = gp[i];
  }
  __syncthreads();  // B3
  f32x4 qacc[8];
  gemm_frag(af, Ws, m, q, qacc);
#pragma unroll
  for (int nt = 0; nt < 8; nt++) qacc[nt] += bQ[nt * 16 + m];
  __syncthreads();  // B4
  {
    us16x8* lp = (us16x8*)&Ws[sr][sh * 64];
#pragma unroll
    for (int i = 0; i < 8; i++) lp[i] = pf[i];
  }
  __syncthreads();  // B5
  f32x4 vacc[8];
  gemm_frag(af, Ws, m, q, vacc);
#pragma unroll
  for (int nt = 0; nt < 8; nt++) vacc[nt] += bV[nt * 16 + m];

  // ---- cross-head attention, per output row r (round-4/5 verbatim)
  unsigned short* Wh = Whall + (size_t)et * nrows * D;
  const float scale = 0.17677669529663687f;  // 1/sqrt(32)
#pragma unroll
  for (int r = 0; r < 4; r++) {
    float sc[4][4];
#pragma unroll
    for (int hh = 0; hh < 4; hh++)
#pragma unroll
      for (int gg = 0; gg < 4; gg++)
        sc[hh][gg] = qacc[2 * hh][r] * kacc[2 * gg][r] + qacc[2 * hh + 1][r] * kacc[2 * gg + 1][r];
#pragma unroll
    for (int off = 1; off < 16; off <<= 1)
#pragma unroll
      for (int hh = 0; hh < 4; hh++)
#pragma unroll
        for (int gg = 0; gg < 4; gg++)
          sc[hh][gg] += __shfl_xor(sc[hh][gg], off, 64);
    float a[4][4];
#pragma unroll
    for (int hh = 0; hh < 4; hh++) {
      float s0 = sc[hh][0] * scale, s1 = sc[hh][1] * scale;
      float s2 = sc[hh][2] * scale, s3 = sc[hh][3] * scale;
      float mx = fmaxf(fmaxf(s0, s1), fmaxf(s2, s3));
      float e0 = __expf(s0 - mx), e1 = __expf(s1 - mx);
      float e2 = __expf(s2 - mx), e3 = __expf(s3 - mx);
      float inv = 1.f / (e0 + e1 + e2 + e3);
      a[hh][0] = e0 * inv; a[hh][1] = e1 * inv; a[hh][2] = e2 * inv; a[hh][3] = e3 * inv;
    }
    int grow = row0 + w * 16 + q * 4 + r;
    if (grow < nrows) {
      unsigned short* op = Wh + (size_t)grow * D;
#pragma unroll
      for (int nt = 0; nt < 8; nt++) {
        int hh = nt >> 1, lo = nt & 1;
        float o = a[hh][0] * vacc[0 + lo][r] + a[hh][1] * vacc[2 + lo][r] +
                  a[hh][2] * vacc[4 + lo][r] + a[hh][3] * vacc[6 + lo][r];
        op[nt * 16 + m] = f2b(o);
      }
    }
  }
}

// ---- bucket build: per (etype,dst) list of src ids (+et*N so Whall is one base) ----
__global__ void k_build(const int* __restrict__ src, const int* __restrict__ dst,
                        int* __restrict__ cnt, int* __restrict__ bucket, int Eper, int n) {
  int i = blockIdx.x * 256 + threadIdx.x;
  if (i >= NET * Eper) return;
  int et = i / Eper;
  int d = dst[i];
  int s = src[i];
  int key = et * n + d;
  int slot = atomicAdd(&cnt[key], 1);
  if (slot < CAP) bucket[(size_t)key * CAP + slot] = s + et * n;
}

// ---- gather + mean + residual + LayerNorm, one wave per node (round-5 verbatim, passed) ----
__global__ __launch_bounds__(256) void k_gather_ln(
    const unsigned short* __restrict__ Whall, const int* __restrict__ bucket,
    const int* __restrict__ cnt, const float* __restrict__ feat,
    const float* __restrict__ g, const float* __restrict__ b,
    float* __restrict__ out, int n) {
  int lane = threadIdx.x & 63, wv = threadIdx.x >> 6;
  int node = blockIdx.x * 4 + wv;
  if (node >= n) return;

  int c0 = cnt[node], c1 = cnt[n + node];
  int c0c = min(c0, CAP), c1c = min(c1, CAP);
  float w0 = 1.0f / fmaxf((float)c0, 1.0f);
  float w1 = 1.0f / fmaxf((float)c1, 1.0f);

  // preload edge ids: lanes 0..31 hold etype-0 ids, lanes 32..63 hold etype-1 ids
  int myid = 0;
  if (lane < 32) {
    if (lane < c0c) myid = bucket[(size_t)node * CAP + lane];
  } else {
    if (lane - 32 < c1c) myid = bucket[((size_t)n + node) * CAP + (lane - 32)];
  }

  float a0 = 0.f, a1 = 0.f;  // columns 2*lane, 2*lane+1
  for (int j = 0; j < c0c; j++) {
    int sid = __shfl(myid, j, 64);
    ushort2 v = *(const ushort2*)(Whall + (size_t)sid * D + 2 * lane);
    a0 += w0 * b2f(v.x);
    a1 += w0 * b2f(v.y);
  }
  for (int j = 0; j < c1c; j++) {
    int sid = __shfl(myid, 32 + j, 64);
    ushort2 v = *(const ushort2*)(Whall + (size_t)sid * D + 2 * lane);
    a0 += w1 * b2f(v.x);
    a1 += w1 * b2f(v.y);
  }

  const float2* fp = (const float2*)(feat + (size_t)node * D);
  float2 fv = fp[lane];
  float x0 = a0 + fv.x;
  float x1 = a1 + fv.y;

  float s = x0 + x1, s2 = x0 * x0 + x1 * x1;
#pragma unroll
  for (int off = 32; off > 0; off >>= 1) {
    s += __shfl_xor(s, off, 64);
    s2 += __shfl_xor(s2, off, 64);
  }
  float mu = s * (1.0f / 128.0f);
  float var = fmaxf(s2 * (1.0f / 128.0f) - mu * mu, 0.0f);
  float rs = rsqrtf(var + 1e-5f);

  float2 gv = ((const float2*)g)[lane];
  float2 bv = ((const float2*)b)[lane];
  float2 ov;
  ov.x = (x0 - mu) * rs * gv.x + bv.x;
  ov.y = (x1 - mu) * rs * gv.y + bv.y;
  ((float2*)(out + (size_t)node * D))[lane] = ov;
}

extern "C" void kernel_launch(void* const* d_in, const int* in_sizes, int n_in,
                              void* d_out, int out_size, void* d_ws, size_t ws_size,
                              hipStream_t stream) {
  const float* feat = (const float*)d_in[0];
  const int* src = (const int*)d_in[1];
  const int* dst = (const int*)d_in[2];
  const float* Wt = (const float*)d_in[3];
  const float* bt = (const float*)d_in[4];
  const float* Kw = (const float*)d_in[5];
  const float* Kb = (const float*)d_in[6];
  const float* Qw = (const float*)d_in[7];
  const float* Qb = (const float*)d_in[8];
  const float* Vw = (const float*)d_in[9];
  const float* Vb = (const float*)d_in[10];
  const float* lng = (const float*)d_in[11];
  const float* lnb = (const float*)d_in[12];

  const int N = in_sizes[0] / D;       // 100000
  const int E = in_sizes[1] / NET;     // 800000

  // workspace: Whall 51.2MB + bucket 25.6MB + cnt 0.8MB + WTc 0.2MB + bc 3KB ~= 77.8MB
  char* p = (char*)d_ws;
  unsigned short* Whall = (unsigned short*)p;  p += (size_t)NET * N * D * 2;
  int* bucket = (int*)p;                       p += (size_t)NET * N * CAP * sizeof(int);
  int* cnt = (int*)p;                          p += (size_t)NET * N * sizeof(int);
  unsigned short* WTc = (unsigned short*)p;    p += (size_t)NET * 3 * D * D * 2;
  float* bc = (float*)p;

  hipMemsetAsync(cnt, 0, (size_t)NET * N * sizeof(int), stream);
  k_combine<<<dim3(8, NET * 3), 256, 0, stream>>>(Wt, bt, Kw, Kb, Qw, Qb, Vw, Vb, WTc, bc);
  k_build<<<(NET * E + 255) / 256, 256, 0, stream>>>(src, dst, cnt, bucket, E, N);

  int gblocks = (N + 63) / 64;
  k_fused<<<dim3(gblocks, NET), 256, 0, stream>>>(feat, WTc, bc, Whall, N);

  k_gather_ln<<<(N + 3) / 4, 256, 0, stream>>>(Whall, bucket, cnt, feat, lng, lnb,
                                               (float*)d_out, N);
}

// Round 8
// 428.124 us; speedup vs baseline: 1.2724x; 1.0794x over previous
//
#include <hip/hip_runtime.h>
#include <hip/hip_bf16.h>
#include <stdint.h>

#define D 128
#define NET 2
#define CAP 32   // max stored in-edges per node per etype (deg ~ Poisson(8); true cnt still used for 1/deg)

typedef __bf16 bf16x8 __attribute__((ext_vector_type(8)));
typedef float f32x4 __attribute__((ext_vector_type(4)));
typedef short s16x8 __attribute__((ext_vector_type(8)));
typedef unsigned short us16x8 __attribute__((ext_vector_type(8)));

__device__ __forceinline__ float b2f(unsigned short u) {
  return __builtin_bit_cast(float, ((uint32_t)u) << 16);
}
__device__ __forceinline__ unsigned short f2b(float f) {
  __hip_bfloat16 h = __float2bfloat16(f);
  return __builtin_bit_cast(unsigned short, h);
}

// ---- combine weights: WTc[combo][n][k] = bf16( (W0 @ W1)^T ), bc = b0@W1 + b1 ----
// combo = et*3 + which, which in {K,Q,V}. All math fp32.  (round-5 verbatim, passed)
__global__ void k_combine(const float* __restrict__ Wt, const float* __restrict__ bt,
                          const float* __restrict__ Kw, const float* __restrict__ Kb,
                          const float* __restrict__ Qw, const float* __restrict__ Qb,
                          const float* __restrict__ Vw, const float* __restrict__ Vb,
                          unsigned short* __restrict__ WTc, float* __restrict__ bc) {
  int combo = blockIdx.y;
  int et = combo / 3, which = combo % 3;
  const float* W0 = Wt + (size_t)et * D * D;
  const float* W1 = ((which == 0) ? Kw : (which == 1) ? Qw : Vw) + (size_t)et * D * D;
  const float* b1 = ((which == 0) ? Kb : (which == 1) ? Qb : Vb) + (size_t)et * D;
  const float* b0 = bt + (size_t)et * D;

  int t = threadIdx.x;
  int i = blockIdx.x * 16 + (t >> 4);
  int jb = (t & 15) * 8;
  float acc[8];
#pragma unroll
  for (int j = 0; j < 8; j++) acc[j] = 0.f;
  for (int k = 0; k < D; k++) {
    float a0 = W0[(size_t)i * D + k];
    const float* w1p = W1 + (size_t)k * D + jb;
#pragma unroll
    for (int j = 0; j < 8; j++) acc[j] += a0 * w1p[j];
  }
  unsigned short* wout = WTc + (size_t)combo * D * D;
#pragma unroll
  for (int j = 0; j < 8; j++) wout[(size_t)(jb + j) * D + i] = f2b(acc[j]);

  if (blockIdx.x == 0 && t < D) {
    float s = b1[t];
    for (int k = 0; k < D; k++) s += b0[k] * W1[(size_t)k * D + t];
    bc[(size_t)combo * D + t] = s;
  }
}

// stage one 128x128 bf16 weight (row-major [out][in]) into LDS, 256 threads (round-4 verbatim)
__device__ __forceinline__ void stage_w(const unsigned short* __restrict__ W,
                                        unsigned short (*Ws)[136], int tid) {
  int r = tid >> 1, hh = tid & 1;
  const us16x8* gp = (const us16x8*)(W + (size_t)r * D + hh * 64);
  us16x8* lp = (us16x8*)&Ws[r][hh * 64];
#pragma unroll
  for (int i = 0; i < 8; i++) lp[i] = gp[i];
}

// GEMM of the A-frags (af) against staged B (Ws) -> 8 x f32x4 per lane (round-4 verbatim)
__device__ __forceinline__ void gemm_frag(const bf16x8* af, unsigned short (*Ws)[136],
                                          int m, int q, f32x4* acc) {
#pragma unroll
  for (int nt = 0; nt < 8; nt++) {
    f32x4 a = {0.f, 0.f, 0.f, 0.f};
#pragma unroll
    for (int ks = 0; ks < 4; ks++) {
      s16x8 br = *(const s16x8*)&Ws[nt * 16 + m][ks * 32 + q * 8];
      a = __builtin_amdgcn_mfma_f32_16x16x32_bf16(af[ks], __builtin_bit_cast(bf16x8, br), a, 0, 0, 0);
    }
    acc[nt] = a;
  }
}

// ---- fused per-etype: K/Q/V = feat @ Wc + bc ; cross-head attn -> Wh (bf16) ----
// Round-7 verbatim (passed): LDS staging + combined weights + register prefetch.
__global__ __launch_bounds__(256) void k_fused(
    const float* __restrict__ feat, const unsigned short* __restrict__ WTc,
    const float* __restrict__ bc, unsigned short* __restrict__ Whall, int nrows) {
  __shared__ unsigned short As[64][136];
  __shared__ unsigned short Ws[128][136];
  int et = blockIdx.y;
  int tid = threadIdx.x;
  int row0 = blockIdx.x * 64;
  int w = tid >> 6, lane = tid & 63;
  int m = lane & 15, q = lane >> 4;

  const unsigned short* WK = WTc + (size_t)(et * 3 + 0) * D * D;
  const unsigned short* WQ = WTc + (size_t)(et * 3 + 1) * D * D;
  const unsigned short* WV = WTc + (size_t)(et * 3 + 2) * D * D;
  const float* bK = bc + (size_t)(et * 3 + 0) * D;
  const float* bQ = bc + (size_t)(et * 3 + 1) * D;
  const float* bV = bc + (size_t)(et * 3 + 2) * D;

  {  // stage feat tile (64 x 128), fp32 -> bf16, coalesced
    int r = tid >> 2, qq = tid & 3;
    int gr = row0 + r;
    unsigned short tmp[32];
    if (gr < nrows) {
      const f32x4* gp = (const f32x4*)(feat + (size_t)gr * D + qq * 32);
#pragma unroll
      for (int i = 0; i < 8; i++) {
        f32x4 v = gp[i];
#pragma unroll
        for (int j = 0; j < 4; j++) tmp[i * 4 + j] = f2b(v[j]);
      }
    } else {
#pragma unroll
      for (int i = 0; i < 32; i++) tmp[i] = 0;
    }
    us16x8* lp = (us16x8*)&As[r][qq * 32];
#pragma unroll
    for (int i = 0; i < 4; i++) lp[i] = *(const us16x8*)&tmp[i * 8];
  }
  stage_w(WK, Ws, tid);
  __syncthreads();  // B1

  bf16x8 af[4];
#pragma unroll
  for (int ks = 0; ks < 4; ks++)
    af[ks] = __builtin_bit_cast(bf16x8, *(const s16x8*)&As[w * 16 + m][ks * 32 + q * 8]);

  // prefetch WQ into registers (same addressing as stage_w) while K-GEMM runs
  int sr = tid >> 1, sh = tid & 1;
  us16x8 pf[8];
  {
    const us16x8* gp = (const us16x8*)(WQ + (size_t)sr * D + sh * 64);
#pragma unroll
    for (int i = 0; i < 8; i++) pf[i] = gp[i];
  }
  f32x4 kacc[8];
  gemm_frag(af, Ws, m, q, kacc);
#pragma unroll
  for (int nt = 0; nt < 8; nt++) kacc[nt] += bK[nt * 16 + m];
  __syncthreads();  // B2: all K reads of Ws done
  {
    us16x8* lp = (us16x8*)&Ws[sr][sh * 64];
#pragma unroll
    for (int i = 0; i < 8; i++) lp[i] = pf[i];
  }
  {  // prefetch WV during Q-GEMM
    const us16x8* gp = (const us16x8*)(WV + (size_t)sr * D + sh * 64);
#pragma unroll
    for (int i = 0; i < 8; i++) pf[i] = gp[i];
  }
  __syncthreads();  // B3
  f32x4 qacc[8];
  gemm_frag(af, Ws, m, q, qacc);
#pragma unroll
  for (int nt = 0; nt < 8; nt++) qacc[nt] += bQ[nt * 16 + m];
  __syncthreads();  // B4
  {
    us16x8* lp = (us16x8*)&Ws[sr][sh * 64];
#pragma unroll
    for (int i = 0; i < 8; i++) lp[i] = pf[i];
  }
  __syncthreads();  // B5
  f32x4 vacc[8];
  gemm_frag(af, Ws, m, q, vacc);
#pragma unroll
  for (int nt = 0; nt < 8; nt++) vacc[nt] += bV[nt * 16 + m];

  // ---- cross-head attention, per output row r (C layout: row=q*4+r, col=nt*16+m)
  unsigned short* Wh = Whall + (size_t)et * nrows * D;
  const float scale = 0.17677669529663687f;  // 1/sqrt(32)
#pragma unroll
  for (int r = 0; r < 4; r++) {
    float sc[4][4];
#pragma unroll
    for (int hh = 0; hh < 4; hh++)
#pragma unroll
      for (int gg = 0; gg < 4; gg++)
        sc[hh][gg] = qacc[2 * hh][r] * kacc[2 * gg][r] + qacc[2 * hh + 1][r] * kacc[2 * gg + 1][r];
#pragma unroll
    for (int off = 1; off < 16; off <<= 1)
#pragma unroll
      for (int hh = 0; hh < 4; hh++)
#pragma unroll
        for (int gg = 0; gg < 4; gg++)
          sc[hh][gg] += __shfl_xor(sc[hh][gg], off, 64);
    float a[4][4];
#pragma unroll
    for (int hh = 0; hh < 4; hh++) {
      float s0 = sc[hh][0] * scale, s1 = sc[hh][1] * scale;
      float s2 = sc[hh][2] * scale, s3 = sc[hh][3] * scale;
      float mx = fmaxf(fmaxf(s0, s1), fmaxf(s2, s3));
      float e0 = __expf(s0 - mx), e1 = __expf(s1 - mx);
      float e2 = __expf(s2 - mx), e3 = __expf(s3 - mx);
      float inv = 1.f / (e0 + e1 + e2 + e3);
      a[hh][0] = e0 * inv; a[hh][1] = e1 * inv; a[hh][2] = e2 * inv; a[hh][3] = e3 * inv;
    }
    int grow = row0 + w * 16 + q * 4 + r;
    if (grow < nrows) {
      unsigned short* op = Wh + (size_t)grow * D;
#pragma unroll
      for (int nt = 0; nt < 8; nt++) {
        int hh = nt >> 1, lo = nt & 1;
        float o = a[hh][0] * vacc[0 + lo][r] + a[hh][1] * vacc[2 + lo][r] +
                  a[hh][2] * vacc[4 + lo][r] + a[hh][3] * vacc[6 + lo][r];
        op[nt * 16 + m] = f2b(o);
      }
    }
  }
}

// ---- bucket build: per (etype,dst) list of src ids (+et*N so Whall is one base) ----
__global__ void k_build(const int* __restrict__ src, const int* __restrict__ dst,
                        int* __restrict__ cnt, int* __restrict__ bucket, int Eper, int n) {
  int i = blockIdx.x * 256 + threadIdx.x;
  if (i >= NET * Eper) return;
  int et = i / Eper;
  int d = dst[i];
  int s = src[i];
  int key = et * n + d;
  int slot = atomicAdd(&cnt[key], 1);
  if (slot < CAP) bucket[(size_t)key * CAP + slot] = s + et * n;
}

// ---- gather + mean + residual + LayerNorm, one wave per node ----
// Unroll-8 masked gather: 8 independent loads in flight per wave (MLP 1 -> 8).
__global__ __launch_bounds__(256) void k_gather_ln(
    const unsigned short* __restrict__ Whall, const int* __restrict__ bucket,
    const int* __restrict__ cnt, const float* __restrict__ feat,
    const float* __restrict__ g, const float* __restrict__ b,
    float* __restrict__ out, int n) {
  int lane = threadIdx.x & 63, wv = threadIdx.x >> 6;
  int node = blockIdx.x * 4 + wv;
  if (node >= n) return;

  int c0 = cnt[node], c1 = cnt[n + node];
  int c0c = min(c0, CAP), c1c = min(c1, CAP);
  float w0 = 1.0f / fmaxf((float)c0, 1.0f);
  float w1 = 1.0f / fmaxf((float)c1, 1.0f);

  // preload edge ids: lanes 0..31 hold etype-0 ids, lanes 32..63 hold etype-1 ids
  int myid = 0;
  if (lane < 32) {
    if (lane < c0c) myid = bucket[(size_t)node * CAP + lane];
  } else {
    if (lane - 32 < c1c) myid = bucket[((size_t)n + node) * CAP + (lane - 32)];
  }

  float a0 = 0.f, a1 = 0.f;  // columns 2*lane, 2*lane+1
  for (int j = 0; j < c0c; j += 8) {
    int sid[8]; float wt[8];
#pragma unroll
    for (int u = 0; u < 8; u++) {
      int jj = j + u;
      bool v = jj < c0c;
      sid[u] = __shfl(myid, v ? jj : 0, 64);
      wt[u] = v ? w0 : 0.f;
    }
    ushort2 vv[8];
#pragma unroll
    for (int u = 0; u < 8; u++)
      vv[u] = *(const ushort2*)(Whall + (size_t)sid[u] * D + 2 * lane);
#pragma unroll
    for (int u = 0; u < 8; u++) {
      a0 += wt[u] * b2f(vv[u].x);
      a1 += wt[u] * b2f(vv[u].y);
    }
  }
  for (int j = 0; j < c1c; j += 8) {
    int sid[8]; float wt[8];
#pragma unroll
    for (int u = 0; u < 8; u++) {
      int jj = j + u;
      bool v = jj < c1c;
      sid[u] = __shfl(myid, v ? 32 + jj : 32, 64);
      wt[u] = v ? w1 : 0.f;
    }
    ushort2 vv[8];
#pragma unroll
    for (int u = 0; u < 8; u++)
      vv[u] = *(const ushort2*)(Whall + (size_t)sid[u] * D + 2 * lane);
#pragma unroll
    for (int u = 0; u < 8; u++) {
      a0 += wt[u] * b2f(vv[u].x);
      a1 += wt[u] * b2f(vv[u].y);
    }
  }

  const float2* fp = (const float2*)(feat + (size_t)node * D);
  float2 fv = fp[lane];
  float x0 = a0 + fv.x;
  float x1 = a1 + fv.y;

  float s = x0 + x1, s2 = x0 * x0 + x1 * x1;
#pragma unroll
  for (int off = 32; off > 0; off >>= 1) {
    s += __shfl_xor(s, off, 64);
    s2 += __shfl_xor(s2, off, 64);
  }
  float mu = s * (1.0f / 128.0f);
  float var = fmaxf(s2 * (1.0f / 128.0f) - mu * mu, 0.0f);
  float rs = rsqrtf(var + 1e-5f);

  float2 gv = ((const float2*)g)[lane];
  float2 bv = ((const float2*)b)[lane];
  float2 ov;
  ov.x = (x0 - mu) * rs * gv.x + bv.x;
  ov.y = (x1 - mu) * rs * gv.y + bv.y;
  ((float2*)(out + (size_t)node * D))[lane] = ov;
}

extern "C" void kernel_launch(void* const* d_in, const int* in_sizes, int n_in,
                              void* d_out, int out_size, void* d_ws, size_t ws_size,
                              hipStream_t stream) {
  const float* feat = (const float*)d_in[0];
  const int* src = (const int*)d_in[1];
  const int* dst = (const int*)d_in[2];
  const float* Wt = (const float*)d_in[3];
  const float* bt = (const float*)d_in[4];
  const float* Kw = (const float*)d_in[5];
  const float* Kb = (const float*)d_in[6];
  const float* Qw = (const float*)d_in[7];
  const float* Qb = (const float*)d_in[8];
  const float* Vw = (const float*)d_in[9];
  const float* Vb = (const float*)d_in[10];
  const float* lng = (const float*)d_in[11];
  const float* lnb = (const float*)d_in[12];

  const int N = in_sizes[0] / D;       // 100000
  const int E = in_sizes[1] / NET;     // 800000

  // workspace: Whall 51.2MB + bucket 25.6MB + cnt 0.8MB + WTc 0.2MB + bc 3KB ~= 77.8MB
  char* p = (char*)d_ws;
  unsigned short* Whall = (unsigned short*)p;  p += (size_t)NET * N * D * 2;
  int* bucket = (int*)p;                       p += (size_t)NET * N * CAP * sizeof(int);
  int* cnt = (int*)p;                          p += (size_t)NET * N * sizeof(int);
  unsigned short* WTc = (unsigned short*)p;    p += (size_t)NET * 3 * D * D * 2;
  float* bc = (float*)p;

  hipMemsetAsync(cnt, 0, (size_t)NET * N * sizeof(int), stream);
  k_combine<<<dim3(8, NET * 3), 256, 0, stream>>>(Wt, bt, Kw, Kb, Qw, Qb, Vw, Vb, WTc, bc);
  k_build<<<(NET * E + 255) / 256, 256, 0, stream>>>(src, dst, cnt, bucket, E, N);

  int gblocks = (N + 63) / 64;
  k_fused<<<dim3(gblocks, NET), 256, 0, stream>>>(feat, WTc, bc, Whall, N);

  k_gather_ln<<<(N + 3) / 4, 256, 0, stream>>>(Whall, bucket, cnt, feat, lng, lnb,
                                               (float*)d_out, N);
}